// Round 1
// 336.656 us; speedup vs baseline: 1.1450x; 1.1450x over previous
//
#include <hip/hip_runtime.h>
#include <math.h>

// ---------------------------------------------------------------------------
// 3-layer GCN, CSR-gather formulation.
// Round 14: atomic-free CSR build via two-level counting sort.
//   Old: k_hist_rank did 1.2M device-scope atomics -> 42 MB of ~32B/atomic
//   write-through traffic at 11% HBM (52 us), plus a random-scatter pass.
//   New: bucket (dst>>9, 512 nodes/bucket) histogram in LDS -> scan the
//   [bucket][block] matrix -> deterministic bucket scatter (LDS cursors) ->
//   per-bucket CSR finalize (LDS hist + scan + rank). Zero global atomics.
//   CSR output layout (rp/esrc/dis) identical; gemm/agg/w3lsm untouched.
// N=100000, E=1200000, F: 128 -> 64 -> 64 -> 40
// ---------------------------------------------------------------------------

static inline int cdiv(long a, int b) { return (int)((a + b - 1) / b); }

// ---- bf16 helpers (RNE) ----
__device__ __forceinline__ unsigned short f2bf(float f) {
    unsigned u = __float_as_uint(f);
    u += 0x7fffu + ((u >> 16) & 1u);
    return (unsigned short)(u >> 16);
}
__device__ __forceinline__ float bf2f(unsigned short b) {
    return __uint_as_float(((unsigned)b) << 16);
}

// ---- radix-bucket CSR build ----
#define RSH 9
#define RNODES 512            // 1 << RSH nodes per bucket
#define GB 256                // blocks in bucket-hist / bucket-scatter passes
#define NBMAX 256             // max buckets (N <= 131072)

// K1: per-block bucket histogram (LDS atomics only).
// bh[b*GB + blk] = #edges in block blk's chunk with dst in bucket b.
__global__ __launch_bounds__(256)
void k_bhist(const int* __restrict__ dst, int* __restrict__ bh,
             int E, int NB, int EPB) {
    __shared__ int bcnt[NBMAX];
    const int tid = threadIdx.x, blk = blockIdx.x;
    for (int i = tid; i < NB; i += 256) bcnt[i] = 0;
    __syncthreads();
    const int e1 = min(E, (blk + 1) * EPB);
    for (int e = blk * EPB + tid; e < e1; e += 256)
        atomicAdd(&bcnt[dst[e] >> RSH], 1);
    __syncthreads();
    for (int i = tid; i < NB; i += 256) bh[i * GB + blk] = bcnt[i];
}

// K2: scatter edges into bucket-grouped ebuf. Each (block,bucket) pair owns
// a disjoint range from the scanned offsets -> no global atomics; writes are
// short contiguous runs per stream (L2-combinable).
__global__ __launch_bounds__(256)
void k_bscatter(const int* __restrict__ src, const int* __restrict__ dst,
                const int* __restrict__ eoff, int2* __restrict__ ebuf,
                int E, int NB, int EPB) {
    __shared__ int cur[NBMAX];
    const int tid = threadIdx.x, blk = blockIdx.x;
    for (int i = tid; i < NB; i += 256) cur[i] = eoff[i * GB + blk];
    __syncthreads();
    const int e1 = min(E, (blk + 1) * EPB);
    for (int e = blk * EPB + tid; e < e1; e += 256) {
        int d = dst[e];
        int s = src[e];
        int pos = atomicAdd(&cur[d >> RSH], 1);
        ebuf[pos] = make_int2(d, s);
    }
}

// K3: per-bucket CSR finalize. One block per bucket: LDS degree histogram,
// LDS exclusive scan (rp = bucket_base + local), dis, rank-scatter into esrc.
__global__ __launch_bounds__(1024)
void k_csr(const int2* __restrict__ ebuf, const int* __restrict__ eoff,
           int* __restrict__ rp, float* __restrict__ dis, int* __restrict__ esrc,
           int N, int E, int NB) {
    __shared__ int cnt[RNODES];
    __shared__ int cur[RNODES];
    __shared__ int sm[1024];
    const int tid = threadIdx.x, b = blockIdx.x;
    const int node0 = b << RSH;
    const int bb = eoff[b * GB];
    const int be = (b + 1 == NB) ? E : eoff[(b + 1) * GB];

    if (tid < RNODES) cnt[tid] = 0;
    __syncthreads();
    for (int e = bb + tid; e < be; e += 1024)
        atomicAdd(&cnt[ebuf[e].x - node0], 1);
    __syncthreads();

    // exclusive scan of cnt[0..512) (Hillis-Steele; all 1024 threads hit barriers)
    int v = (tid < RNODES) ? cnt[tid] : 0;
    sm[tid] = v;
    __syncthreads();
    for (int off = 1; off < RNODES; off <<= 1) {
        int t = (tid >= off) ? sm[tid - off] : 0;
        __syncthreads();
        sm[tid] += t;
        __syncthreads();
    }
    if (tid < RNODES) {
        int excl = sm[tid] - v;
        cur[tid] = excl;
        int node = node0 + tid;
        if (node < N) {
            rp[node] = bb + excl;
            dis[node] = rsqrtf(1.0f + (float)v);   // +1 self-loop
        }
    }
    if (b == 0 && tid == 0) rp[N] = E;
    __syncthreads();

    for (int e = bb + tid; e < be; e += 1024) {
        int2 ev = ebuf[e];
        int slot = atomicAdd(&cur[ev.x - node0], 1);
        esrc[bb + slot] = ev.y;
    }
}

// ---- 3-step exclusive scan (reused for the [bucket][block] matrix) ----
#define SCAN_B 1024
__global__ void k_scan1(const int* __restrict__ cnt, int* __restrict__ rp,
                        int* __restrict__ bsum, int n) {
    __shared__ int sm[SCAN_B];
    const int tid = threadIdx.x;
    const int gid = blockIdx.x * SCAN_B + tid;
    int v = (gid < n) ? cnt[gid] : 0;
    sm[tid] = v;
    __syncthreads();
    for (int off = 1; off < SCAN_B; off <<= 1) {
        int t = (tid >= off) ? sm[tid - off] : 0;
        __syncthreads();
        sm[tid] += t;
        __syncthreads();
    }
    if (gid < n) rp[gid] = sm[tid] - v;           // exclusive
    if (tid == SCAN_B - 1) bsum[blockIdx.x] = sm[tid];
}

__global__ void k_scan2(int* __restrict__ bsum, int nb) {
    __shared__ int sm[SCAN_B];
    const int tid = threadIdx.x;
    int v = (tid < nb) ? bsum[tid] : 0;
    sm[tid] = v;
    __syncthreads();
    for (int off = 1; off < SCAN_B; off <<= 1) {
        int t = (tid >= off) ? sm[tid - off] : 0;
        __syncthreads();
        sm[tid] += t;
        __syncthreads();
    }
    if (tid < nb) bsum[tid] = sm[tid] - v;        // exclusive
}

__global__ void k_scan3(int* __restrict__ rp, const int* __restrict__ bsum, int n, int E) {
    const int gid = blockIdx.x * SCAN_B + threadIdx.x;
    if (gid < n) rp[gid] += bsum[gid / SCAN_B];
    if (gid == n) rp[n] = E;
}

__device__ __forceinline__ void fma4(float a, const float4& w, float4& acc) {
    acc.x = fmaf(a, w.x, acc.x);
    acc.y = fmaf(a, w.y, acc.y);
    acc.z = fmaf(a, w.z, acc.z);
    acc.w = fmaf(a, w.w, acc.w);
}

// LDS-tiled GEMM with fused dis-scale: Hs[N,64] = (X[N,K] @ W[K,64]) * dis[row].
// BF16OUT: store rows as bf16 (gather target); else fp32.
template<int K, bool BF16OUT>
__global__ __launch_bounds__(256, 2)
void k_gemm_lds(const float* __restrict__ X, const float* __restrict__ W,
                const float* __restrict__ dis, void* __restrict__ Hout, int N) {
    constexpr int KP = K + 4;                 // padded X row stride (floats)
    __shared__ float xs[64 * KP];
    __shared__ float wsh[K * 64];
    const int tid = threadIdx.x;
    const int tx = tid & 15;                  // col group (4 cols)
    const int ty = tid >> 4;                  // row group (4 rows)
    const int row0 = blockIdx.x * 64;

    // stage W: K*16 float4, fully coalesced
    {
        const float4* Wg = (const float4*)W;
        float4* Wl = (float4*)wsh;
#pragma unroll
        for (int i = 0; i < K * 16 / 256; ++i)
            Wl[i * 256 + tid] = Wg[i * 256 + tid];
    }
    // stage X tile: 64 rows x K floats (row-clamped), padded LDS rows
    {
        constexpr int F4 = K / 4;             // float4 per row
        for (int i = tid; i < 64 * F4; i += 256) {
            int r = i / F4, c = i - r * F4;
            int gr = min(row0 + r, N - 1);
            float4 v = *(const float4*)(X + (size_t)gr * K + c * 4);
            *(float4*)(xs + r * KP + c * 4) = v;
        }
    }
    __syncthreads();

    float4 acc0 = {0.f, 0.f, 0.f, 0.f};
    float4 acc1 = {0.f, 0.f, 0.f, 0.f};
    float4 acc2 = {0.f, 0.f, 0.f, 0.f};
    float4 acc3 = {0.f, 0.f, 0.f, 0.f};

    const float* xr0 = xs + (ty * 4 + 0) * KP;
    const float* xr1 = xs + (ty * 4 + 1) * KP;
    const float* xr2 = xs + (ty * 4 + 2) * KP;
    const float* xr3 = xs + (ty * 4 + 3) * KP;

#pragma unroll 2
    for (int k = 0; k < K; k += 4) {
        float4 w0 = *(const float4*)(wsh + (k + 0) * 64 + tx * 4);
        float4 w1 = *(const float4*)(wsh + (k + 1) * 64 + tx * 4);
        float4 w2 = *(const float4*)(wsh + (k + 2) * 64 + tx * 4);
        float4 w3 = *(const float4*)(wsh + (k + 3) * 64 + tx * 4);
        float4 xa = *(const float4*)(xr0 + k);
        float4 xb = *(const float4*)(xr1 + k);
        float4 xc = *(const float4*)(xr2 + k);
        float4 xd = *(const float4*)(xr3 + k);

        fma4(xa.x, w0, acc0); fma4(xa.y, w1, acc0); fma4(xa.z, w2, acc0); fma4(xa.w, w3, acc0);
        fma4(xb.x, w0, acc1); fma4(xb.y, w1, acc1); fma4(xb.z, w2, acc1); fma4(xb.w, w3, acc1);
        fma4(xc.x, w0, acc2); fma4(xc.y, w1, acc2); fma4(xc.z, w2, acc2); fma4(xc.w, w3, acc2);
        fma4(xd.x, w0, acc3); fma4(xd.y, w1, acc3); fma4(xd.z, w2, acc3); fma4(xd.w, w3, acc3);
    }

    const int r = row0 + ty * 4;
#pragma unroll
    for (int i = 0; i < 4; ++i) {
        if (r + i >= N) break;
        float4 a = (i == 0) ? acc0 : (i == 1) ? acc1 : (i == 2) ? acc2 : acc3;
        float d = dis[r + i];
        a.x *= d; a.y *= d; a.z *= d; a.w *= d;
        if (BF16OUT) {
            ushort4 o;
            o.x = f2bf(a.x); o.y = f2bf(a.y); o.z = f2bf(a.z); o.w = f2bf(a.w);
            *(ushort4*)((unsigned short*)Hout + (size_t)(r + i) * 64 + tx * 4) = o;
        } else {
            *(float4*)((float*)Hout + (size_t)(r + i) * 64 + tx * 4) = a;
        }
    }
}

// Wave-per-node segmented row-sum, quad-per-edge, bf16 gather rows (128 B).
// Input Hs = bf16(h*dis).  t = dis[d] * (Hs[d] + sum_{in-edges} Hs[s]).
// MODE 0: A = relu(t + bias)           -> fp32  (layer 1, GEMM input)
// MODE 1: A = relu(t + bias) * dis[d]  -> bf16  (layer 2 -> layer-3 gather)
// MODE 2: A = t                        -> fp32  (layer 3, w3lsm input)
template<int MODE>
__global__ __launch_bounds__(256, 8)
void k_agg(const unsigned short* __restrict__ Hs, const float* __restrict__ dis,
           const int* __restrict__ rp, const int* __restrict__ esrc,
           const float* __restrict__ bias, void* __restrict__ A, int N) {
    const int wave = threadIdx.x >> 6;
    const int lane = threadIdx.x & 63;
    const int node = blockIdx.x * (blockDim.x >> 6) + wave;
    if (node >= N) return;
    const int q  = lane >> 4;          // quad 0..3 -> interleaved edges
    const int f4 = lane & 15;          // 4-feature group within the 64-f row

    const int e0 = rp[node];
    const int e1 = rp[node + 1];
    float4 acc = {0.f, 0.f, 0.f, 0.f};
    int e = e0 + q;
    for (; e + 4 < e1; e += 8) {       // 2 edges per quad per round
        int s0 = esrc[e];
        int s1 = esrc[e + 4];
        ushort4 h0 = *(const ushort4*)(Hs + (size_t)s0 * 64 + f4 * 4);
        ushort4 h1 = *(const ushort4*)(Hs + (size_t)s1 * 64 + f4 * 4);
        acc.x += bf2f(h0.x) + bf2f(h1.x);
        acc.y += bf2f(h0.y) + bf2f(h1.y);
        acc.z += bf2f(h0.z) + bf2f(h1.z);
        acc.w += bf2f(h0.w) + bf2f(h1.w);
    }
    for (; e < e1; e += 4) {
        int s = esrc[e];
        ushort4 h = *(const ushort4*)(Hs + (size_t)s * 64 + f4 * 4);
        acc.x += bf2f(h.x); acc.y += bf2f(h.y); acc.z += bf2f(h.z); acc.w += bf2f(h.w);
    }
    // cross-quad reduce (after: lanes 0..15 hold the full row sum)
    acc.x += __shfl_xor(acc.x, 16, 64);
    acc.y += __shfl_xor(acc.y, 16, 64);
    acc.z += __shfl_xor(acc.z, 16, 64);
    acc.w += __shfl_xor(acc.w, 16, 64);
    acc.x += __shfl_xor(acc.x, 32, 64);
    acc.y += __shfl_xor(acc.y, 32, 64);
    acc.z += __shfl_xor(acc.z, 32, 64);
    acc.w += __shfl_xor(acc.w, 32, 64);

    if (lane < 16) {
        const float dd = dis[node];
        ushort4 sh = *(const ushort4*)(Hs + (size_t)node * 64 + lane * 4);
        float4 v;
        v.x = (acc.x + bf2f(sh.x)) * dd;
        v.y = (acc.y + bf2f(sh.y)) * dd;
        v.z = (acc.z + bf2f(sh.z)) * dd;
        v.w = (acc.w + bf2f(sh.w)) * dd;
        if (MODE == 0 || MODE == 1) {
            float4 bv = ((const float4*)bias)[lane];
            v.x = fmaxf(v.x + bv.x, 0.f);
            v.y = fmaxf(v.y + bv.y, 0.f);
            v.z = fmaxf(v.z + bv.z, 0.f);
            v.w = fmaxf(v.w + bv.w, 0.f);
        }
        if (MODE == 1) {
            v.x *= dd; v.y *= dd; v.z *= dd; v.w *= dd;
            ushort4 o;
            o.x = f2bf(v.x); o.y = f2bf(v.y); o.z = f2bf(v.z); o.w = f2bf(v.w);
            *(ushort4*)((unsigned short*)A + (size_t)node * 64 + lane * 4) = o;
        } else {
            *(float4*)((float*)A + (size_t)node * 64 + lane * 4) = v;
        }
    }
}

// Final layer: out[n,:40] = log_softmax(X[n,:64] @ W3 + b3).
// Lane c holds W3[:,c] in 64 VGPRs; X row via wave-uniform loads.
__global__ __launch_bounds__(256, 4)
void k_w3lsm(const float* __restrict__ X, const float* __restrict__ W,
             const float* __restrict__ bias, float* __restrict__ out,
             int N, int npw) {
    const int wid  = blockIdx.x * (blockDim.x >> 6) + (threadIdx.x >> 6);
    const int lane = threadIdx.x & 63;
    const int cl   = (lane < 40) ? lane : 0;

    float w[64];
#pragma unroll
    for (int k = 0; k < 64; ++k) w[k] = W[k * 40 + cl];
    const float bv = bias[cl];

    const int n0 = wid * npw;
    const int n1 = min(n0 + npw, N);
    for (int node = n0; node < n1; ++node) {
        const int un = __builtin_amdgcn_readfirstlane(node);
        const float4* xr = (const float4*)(X + (size_t)un * 64);
        float acc = 0.0f;
#pragma unroll
        for (int j = 0; j < 16; ++j) {
            float4 xv = xr[j];
            acc = fmaf(xv.x, w[4 * j + 0], acc);
            acc = fmaf(xv.y, w[4 * j + 1], acc);
            acc = fmaf(xv.z, w[4 * j + 2], acc);
            acc = fmaf(xv.w, w[4 * j + 3], acc);
        }
        float v = (lane < 40) ? acc + bv : -INFINITY;
        float m = v;
#pragma unroll
        for (int o = 32; o > 0; o >>= 1) m = fmaxf(m, __shfl_xor(m, o, 64));
        float ex = (lane < 40) ? expf(v - m) : 0.0f;
        float s = ex;
#pragma unroll
        for (int o = 32; o > 0; o >>= 1) s += __shfl_xor(s, o, 64);
        if (lane < 40) out[(size_t)node * 40 + lane] = v - m - logf(s);
    }
}

extern "C" void kernel_launch(void* const* d_in, const int* in_sizes, int n_in,
                              void* d_out, int out_size, void* d_ws, size_t ws_size,
                              hipStream_t stream) {
    const float* x  = (const float*)d_in[0];
    const int*   ei = (const int*)d_in[1];
    const float* W1 = (const float*)d_in[2];
    const float* b1 = (const float*)d_in[3];
    const float* W2 = (const float*)d_in[4];
    const float* b2 = (const float*)d_in[5];
    const float* W3 = (const float*)d_in[6];
    const float* b3 = (const float*)d_in[7];
    float* out = (float*)d_out;

    const int N = in_sizes[0] / 128;
    const int E = in_sizes[1] / 2;
    const int* src = ei;
    const int* dst = ei + E;

    const int NB   = cdiv(N, RNODES);        // buckets (196 @ N=100000)
    const int EPB  = cdiv(E, GB);            // edges per hist/scatter block
    const int nscan = NB * GB;               // scan length (50176)

    // ---- workspace layout ----
    // buf0: ebuf int2 (CSR build) -> Hs1 bf16 -> Hs2 bf16 -> g fp32
    // buf1: a1 fp32 -> a2s bf16
    char* ws = (char*)d_ws;
    char* buf0  = ws;                         ws += (size_t)N * 64 * sizeof(float); // 25.6 MB
    char* buf1  = ws;                         ws += (size_t)N * 64 * sizeof(float); // 25.6 MB
    int*   esrc  = (int*)ws;                  ws += (size_t)E * sizeof(int);        // 4.8 MB
    int*   rp    = (int*)ws;                  ws += (size_t)(N + 1) * sizeof(int);
    int*   bsum  = (int*)ws;                  ws += (size_t)SCAN_B * sizeof(int);
    float* dis   = (float*)ws;                ws += (size_t)N * sizeof(float);
    int*   bh    = (int*)ws;                  ws += (size_t)nscan * sizeof(int);    // 200 KB
    int*   eoff  = (int*)ws;                  ws += (size_t)(nscan + 1) * sizeof(int);
    int2*  ebuf  = (int2*)buf0;               // 9.6 MB, consumed before gemm1 writes buf0

    const int B = 256;
    const int nbs = cdiv(nscan, SCAN_B);

    // ---- CSR build: two-level counting sort, zero global atomics ----
    k_bhist<<<GB, B, 0, stream>>>(dst, bh, E, NB, EPB);
    k_scan1<<<nbs, SCAN_B, 0, stream>>>(bh, eoff, bsum, nscan);
    k_scan2<<<1, SCAN_B, 0, stream>>>(bsum, nbs);
    k_scan3<<<cdiv(nscan + 1, SCAN_B), SCAN_B, 0, stream>>>(eoff, bsum, nscan, E);
    k_bscatter<<<GB, B, 0, stream>>>(src, dst, eoff, ebuf, E, NB, EPB);
    k_csr<<<NB, 1024, 0, stream>>>(ebuf, eoff, rp, dis, esrc, N, E, NB);

    // ---- layer 1: Hs1 = bf16((x@W1)*dis); a1 = relu(dis*sum + b1) fp32 ----
    k_gemm_lds<128, true><<<cdiv(N, 64), B, 0, stream>>>(x, W1, dis, buf0, N);
    k_agg<0><<<cdiv(N, 4), B, 0, stream>>>((const unsigned short*)buf0, dis, rp, esrc, b1, buf1, N);

    // ---- layer 2: Hs2 = bf16((a1@W2)*dis); a2s = bf16(relu(dis*sum+b2)*dis) ----
    k_gemm_lds<64, true><<<cdiv(N, 64), B, 0, stream>>>((const float*)buf1, W2, dis, buf0, N);
    k_agg<1><<<cdiv(N, 4), B, 0, stream>>>((const unsigned short*)buf0, dis, rp, esrc, b2, buf1, N);

    // ---- layer 3: g = dis*(sum of a2s) fp32; out = log_softmax(g@W3 + b3) ----
    k_agg<2><<<cdiv(N, 4), B, 0, stream>>>((const unsigned short*)buf1, dis, rp, esrc, nullptr, buf0, N);
    const int NW = 4096;                       // 1024 blocks x 4 waves
    const int npw = cdiv(N, NW);
    k_w3lsm<<<NW / 4, B, 0, stream>>>((const float*)buf0, W3, b3, out, N, npw);
}